// Round 1
// baseline (874.991 us; speedup 1.0000x reference)
//
#include <hip/hip_runtime.h>
#include <math.h>

// ---------------- problem constants ----------------
#define BB   16
#define NN_  2048
#define KK   20
#define INC  64
#define OUTC 64
#define MAPC 32
#define NFC  192
#define ROWS (BB*NN_)   // 32768

// ---------------- K1: KNN + rel/dis records + minmax partials ----------------
// grid (512, 16), block 256.  4 waves/block, one row per wave.
__global__ __launch_bounds__(256) void k_knn(const float* __restrict__ x,
                                             float* __restrict__ rec,
                                             int*   __restrict__ idxArr,
                                             float* __restrict__ mmPart) {
  __shared__ float px[2048], py[2048], pz[2048];
  __shared__ float listD[4][64];
  __shared__ int   listJ[4][64];
  __shared__ int   cnt[4];
  __shared__ float selD[4][20];
  __shared__ int   selJ[4][20];
  __shared__ float wmn[4], wmx[4];

  const int b = blockIdx.y;
  const int t = threadIdx.x;
  const float* xb = x + (size_t)b * 3 * 2048;
  for (int i = t; i < 2048; i += 256) {
    px[i] = xb[i];
    py[i] = xb[2048 + i];
    pz[i] = xb[4096 + i];
  }
  __syncthreads();

  const int w = t >> 6, lane = t & 63;
  const int n = blockIdx.x * 4 + w;
  const float sx = px[n], sy = py[n], sz = pz[n];

  // pass 1: per-lane min distance over its 32 candidates
  float lmin = 1e30f;
  for (int j = lane; j < 2048; j += 64) {
    float dx = px[j] - sx, dy = py[j] - sy, dz = pz[j] - sz;
    float d = fmaf(dx, dx, fmaf(dy, dy, dz * dz));
    lmin = fminf(lmin, d);
  }
  // T = 20th smallest of the 64 lane-mins  (provably >= true d20)
  float v = lmin, T = 0.f;
  for (int r = 0; r < 20; ++r) {
    float m = v;
    for (int s = 1; s < 64; s <<= 1) m = fminf(m, __shfl_xor(m, s));
    unsigned long long mask = __ballot(v == m);
    int winner = (int)__builtin_ctzll(mask);
    if (lane == winner) v = 1e30f;
    T = m;
  }
  if (lane == 0) cnt[w] = 0;
  // pass 2: collect all candidates with d <= T
  for (int j = lane; j < 2048; j += 64) {
    float dx = px[j] - sx, dy = py[j] - sy, dz = pz[j] - sz;
    float d = fmaf(dx, dx, fmaf(dy, dy, dz * dz));
    if (d <= T) {
      int slot = atomicAdd(&cnt[w], 1);
      if (slot < 64) { listD[w][slot] = d; listJ[w][slot] = j; }
    }
  }
  int M = cnt[w];

  if (M > 64) {
    // exact fallback (expected never on random data): 20 full scans
    float lastD = -1.f; int lastJ = -1;
    for (int r = 0; r < 20; ++r) {
      float bd = 1e30f; int bj = 0x7fffffff;
      for (int j = lane; j < 2048; j += 64) {
        float dx = px[j] - sx, dy = py[j] - sy, dz = pz[j] - sz;
        float d = fmaf(dx, dx, fmaf(dy, dy, dz * dz));
        bool valid = (d > lastD) || (d == lastD && j > lastJ);
        if (valid && (d < bd || (d == bd && j < bj))) { bd = d; bj = j; }
      }
      for (int s = 1; s < 64; s <<= 1) {
        float od = __shfl_xor(bd, s); int oj = __shfl_xor(bj, s);
        if (od < bd || (od == bd && oj < bj)) { bd = od; bj = oj; }
      }
      if (lane == 0) { selD[w][r] = bd; selJ[w][r] = bj; }
      lastD = bd; lastJ = bj;
    }
  } else {
    float d = (lane < M) ? listD[w][lane] : 1e30f;
    int   j = (lane < M) ? listJ[w][lane] : 0x7fffffff;
    float lastD = -1.f; int lastJ = -1;
    for (int r = 0; r < 20; ++r) {
      bool valid = (d > lastD) || (d == lastD && j > lastJ);
      float bd = valid ? d : 1e30f;
      int   bj = valid ? j : 0x7fffffff;
      for (int s = 1; s < 64; s <<= 1) {
        float od = __shfl_xor(bd, s); int oj = __shfl_xor(bj, s);
        if (od < bd || (od == bd && oj < bj)) { bd = od; bj = oj; }
      }
      if (lane == 0) { selD[w][r] = bd; selJ[w][r] = bj; }
      lastD = bd; lastJ = bj;
    }
  }
  __syncthreads();

  // write records + per-row min/max contribution
  float row_mn = 1e30f, row_mx = -1e30f;
  const size_t row = (size_t)b * 2048 + n;
  if (lane < 20) {
    int   j = selJ[w][lane];
    float d = selD[w][lane];
    idxArr[row * 20 + lane] = j;
    float rx = px[j] - sx, ry = py[j] - sy, rz = pz[j] - sz;
    float dis = sqrtf(d);
    float* rp = rec + row * 88;
    rp[4 + lane]  = dis;
    rp[24 + lane] = rx;
    rp[44 + lane] = ry;
    rp[64 + lane] = rz;
    row_mn = fminf(fminf(rx, ry), fminf(rz, dis));
    row_mx = fmaxf(fmaxf(rx, ry), fmaxf(rz, dis));
    if (lane == 0) {
      rp[0] = sx; rp[1] = sy; rp[2] = sz; rp[3] = 0.f;
      row_mn = fminf(row_mn, fminf(fminf(sx, sy), sz));
      row_mx = fmaxf(row_mx, fmaxf(fmaxf(sx, sy), sz));
    }
  }
  for (int s = 1; s < 64; s <<= 1) {
    row_mn = fminf(row_mn, __shfl_xor(row_mn, s));
    row_mx = fmaxf(row_mx, __shfl_xor(row_mx, s));
  }
  if (lane == 0) { wmn[w] = row_mn; wmx[w] = row_mx; }
  __syncthreads();
  if (t == 0) {
    float mn = fminf(fminf(wmn[0], wmn[1]), fminf(wmn[2], wmn[3]));
    float mx = fmaxf(fmaxf(wmx[0], wmx[1]), fmaxf(wmx[2], wmx[3]));
    int bid = blockIdx.y * 512 + blockIdx.x;
    mmPart[bid * 2]     = mn;
    mmPart[bid * 2 + 1] = mx;
  }
}

// ---------------- K1b: reduce minmax, build M = ((A+A')/2)@kernels, W1P transpose ----------------
__global__ __launch_bounds__(256) void k_prep(const float* __restrict__ A,
                                              const float* __restrict__ kern,
                                              const float* __restrict__ W1,
                                              const float* __restrict__ mmPart,
                                              float* __restrict__ scal,
                                              float* __restrict__ W1P) {
  __shared__ float smn[256], smx[256];
  const int t = threadIdx.x;
  float mn = 1e30f, mx = -1e30f;
  for (int i = t; i < 8192; i += 256) {
    mn = fminf(mn, mmPart[i * 2]);
    mx = fmaxf(mx, mmPart[i * 2 + 1]);
  }
  smn[t] = mn; smx[t] = mx;
  __syncthreads();
  for (int s = 128; s > 0; s >>= 1) {
    if (t < s) { smn[t] = fminf(smn[t], smn[t + s]); smx[t] = fmaxf(smx[t], smx[t + s]); }
    __syncthreads();
  }
  if (t == 0) scal[0] = smn[0] / (smx[0] - smn[0]);   // c  (ref: x - mn/(mx-mn))
  if (t < 24) {
    int d = t >> 3, e = t & 7;
    float s = 0.f;
    for (int d2 = 0; d2 < 3; ++d2)
      s += 0.5f * (A[d * 3 + d2] + A[d2 * 3 + d]) * kern[d2 * 8 + e];
    scal[1 + t] = s;
  }
  for (int i = t; i < 12288; i += 256) {
    int cp = i >> 6, o = i & 63;
    W1P[cp * 64 + o] = W1[o * 192 + cp];
  }
}

// ---------------- K2: transpose feature (B,64,N) -> featN (B,N,64) ----------------
__global__ __launch_bounds__(256) void k_transpose(const float* __restrict__ f,
                                                   float* __restrict__ fN) {
  __shared__ float tile[64][65];
  const int b = blockIdx.y, n0 = blockIdx.x * 64, t = threadIdx.x;
  const float* fb = f + (size_t)b * 64 * 2048;
  for (int i = t; i < 4096; i += 256) {
    int c = i >> 6, nl = i & 63;
    tile[c][nl] = fb[c * 2048 + n0 + nl];
  }
  __syncthreads();
  float* out = fN + ((size_t)b * 2048 + n0) * 64;
  for (int i = t; i < 4096; i += 256) {
    int nl = i >> 6, c = i & 63;
    out[nl * 64 + c] = tile[c][nl];
  }
}

// ---------------- K3: main per-point compute, 8 points per block ----------------
__global__ __launch_bounds__(256) void k_main(const float* __restrict__ rec,
                                              const int*   __restrict__ idxArr,
                                              const float* __restrict__ featN,
                                              const float* __restrict__ scal,
                                              const float* __restrict__ W1P,
                                              const float* __restrict__ Bf,
                                              const float* __restrict__ onePad,
                                              const float* __restrict__ Wmlp,
                                              const float* __restrict__ bmlp,
                                              const float* __restrict__ b1,
                                              const float* __restrict__ Wout,
                                              float* __restrict__ hT) {
  __shared__ float WmlpL[32 * 65];
  __shared__ float BfL[7 * 32];
  __shared__ float padL[160];
  __shared__ float bmlpL[32];
  __shared__ float b1L[64];
  __shared__ float ML[24];
  __shared__ float cS[1];
  __shared__ float recL[88];
  __shared__ int   idxL[20];
  __shared__ float ffS[20 * 33], ffC[20 * 33];
  __shared__ float feats[96 * 21];
  __shared__ float permL[20 * 9];
  __shared__ float colsumL[8];
  __shared__ float aggB[64 * 196];
  __shared__ __align__(16) float selfF[8 * 64];
  __shared__ int   rowL[8];

  const int t = threadIdx.x;
  // S0: block-constant loads
  for (int i = t; i < 2048; i += 256) WmlpL[(i >> 6) * 65 + (i & 63)] = Wmlp[i];
  if (t < 224) BfL[t] = Bf[t];
  else if (t < 248) ML[t - 224] = scal[1 + (t - 224)];
  else if (t == 248) cS[0] = scal[0];
  for (int i = t; i < 160; i += 256) padL[i] = onePad[i];
  if (t < 32) bmlpL[t] = bmlp[t];
  if (t >= 64 && t < 128) b1L[t - 64] = b1[t - 64];
  __syncthreads();

  const int base = blockIdx.x * 8;
  for (int pp = 0; pp < 8; ++pp) {
    const int row = base + pp;
    const int b   = row >> 11;
    // S1
    if (t < 88) recL[t] = rec[(size_t)row * 88 + t];
    if (t >= 128 && t < 148) idxL[t - 128] = idxArr[(size_t)row * 20 + (t - 128)];
    if (t >= 160 && t < 224) selfF[pp * 64 + (t - 160)] = featN[(size_t)row * 64 + (t - 160)];
    if (t == 224) rowL[pp] = row;
    __syncthreads();

    // S2: Fourier features
    const float c0s = cS[0];
    for (int i = t; i < 640; i += 256) {
      int k = i >> 5, m = i & 31;
      float s = (recL[0] - c0s) * BfL[m]
              + (recL[1] - c0s) * BfL[32 + m]
              + (recL[2] - c0s) * BfL[64 + m]
              + (recL[24 + k] - c0s) * BfL[96 + m]
              + (recL[44 + k] - c0s) * BfL[128 + m]
              + (recL[64 + k] - c0s) * BfL[160 + m]
              + (recL[4 + k]  - c0s) * BfL[192 + m];
      float th = 6.283185307179586f * s;
      float sv, cv;
      __sincosf(th, &sv, &cv);
      ffS[k * 33 + m] = sv;
      ffC[k * 33 + m] = cv;
    }
    __syncthreads();

    // S3: feature gather + x_mlp
    for (int i = t; i < 1280; i += 256) {
      int k = i >> 6, c = i & 63;
      int j = idxL[k];
      feats[c * 21 + k] = featN[((size_t)(b << 11) + j) * 64 + c];
    }
    for (int i = t; i < 640; i += 256) {
      int o = i & 31, k = i >> 5;
      float acc = bmlpL[o];
      #pragma unroll
      for (int m = 0; m < 32; ++m)
        acc = fmaf(ffS[k * 33 + m], WmlpL[o * 65 + m],
                   fmaf(ffC[k * 33 + m], WmlpL[o * 65 + 32 + m], acc));
      feats[(64 + o) * 21 + k] = acc;
    }
    __syncthreads();

    // S4: perm logits + topkmax softmax
    for (int i = t; i < 160; i += 256) {
      int k = i >> 3, e = i & 7;
      permL[k * 9 + e] = recL[24 + k] * ML[e] + recL[44 + k] * ML[8 + e]
                       + recL[64 + k] * ML[16 + e] + padL[k * 8 + e];
    }
    __syncthreads();
    if (t < 8) {
      const int e = t;
      float mx = -1e30f;
      for (int k = 0; k < 20; ++k) mx = fmaxf(mx, permL[k * 9 + e]);
      float pv[20];
      float sum = 0.f;
      #pragma unroll
      for (int k = 0; k < 20; ++k) { pv[k] = expf(permL[k * 9 + e] - mx); sum += pv[k]; }
      float inv = 1.f / sum;
      float s2 = 0.f;
      #pragma unroll
      for (int k = 0; k < 20; ++k) {
        float q = pv[k] * inv;
        q = (q > 0.05f) ? q : 0.f;
        pv[k] = q; s2 += q;
      }
      float inv2 = 1.f / (s2 + 1e-6f);
      #pragma unroll
      for (int k = 0; k < 20; ++k) permL[k * 9 + e] = pv[k] * inv2;
      colsumL[e] = s2 * inv2;
    }
    __syncthreads();

    // S5: agg in shuffled-c' order (rep part collapsed to c0*colsum)
    for (int i = t; i < 1536; i += 256) {
      int e = i & 7, cp = i >> 3;
      int g = cp & 3, r = cp >> 2;
      int u = g * 48 + r;
      float val;
      if (u < 96) {
        val = feats[u * 21] * colsumL[e];
      } else {
        int cu = u - 96;
        float s = 0.f;
        #pragma unroll
        for (int k = 0; k < 20; ++k) s = fmaf(feats[cu * 21 + k], permL[k * 9 + e], s);
        val = s - feats[cu * 21] * colsumL[e];
      }
      aggB[(pp * 8 + e) * 196 + cp] = val;
    }
    __syncthreads();
  }

  // h-stage: (64 rows x 192) @ W1P(192 x 64), register-blocked 2x8 per thread
  const int rp = t >> 3, oo = t & 7;
  const int r0 = rp * 2, r1 = r0 + 1;
  float acc0[8], acc1[8];
  #pragma unroll
  for (int q = 0; q < 8; ++q) { acc0[q] = b1L[oo * 8 + q]; acc1[q] = acc0[q]; }
  #pragma unroll 4
  for (int cp = 0; cp < 192; ++cp) {
    float a0 = aggB[r0 * 196 + cp];
    float a1 = aggB[r1 * 196 + cp];
    const float4 w0 = *(const float4*)(W1P + cp * 64 + oo * 8);
    const float4 w1 = *(const float4*)(W1P + cp * 64 + oo * 8 + 4);
    acc0[0] = fmaf(a0, w0.x, acc0[0]); acc0[1] = fmaf(a0, w0.y, acc0[1]);
    acc0[2] = fmaf(a0, w0.z, acc0[2]); acc0[3] = fmaf(a0, w0.w, acc0[3]);
    acc0[4] = fmaf(a0, w1.x, acc0[4]); acc0[5] = fmaf(a0, w1.y, acc0[5]);
    acc0[6] = fmaf(a0, w1.z, acc0[6]); acc0[7] = fmaf(a0, w1.w, acc0[7]);
    acc1[0] = fmaf(a1, w0.x, acc1[0]); acc1[1] = fmaf(a1, w0.y, acc1[1]);
    acc1[2] = fmaf(a1, w0.z, acc1[2]); acc1[3] = fmaf(a1, w0.w, acc1[3]);
    acc1[4] = fmaf(a1, w1.x, acc1[4]); acc1[5] = fmaf(a1, w1.y, acc1[5]);
    acc1[6] = fmaf(a1, w1.z, acc1[6]); acc1[7] = fmaf(a1, w1.w, acc1[7]);
  }
  // max over the 8 pooling slots (2 local + 2 shuffle levels), then gelu + residual
  float vmx[8];
  #pragma unroll
  for (int q = 0; q < 8; ++q) vmx[q] = fmaxf(acc0[q], acc1[q]);
  #pragma unroll
  for (int q = 0; q < 8; ++q) {
    vmx[q] = fmaxf(vmx[q], __shfl_xor(vmx[q], 8));
    vmx[q] = fmaxf(vmx[q], __shfl_xor(vmx[q], 16));
  }
  const int pt = t >> 5;
  const int mq = (t >> 3) & 3;
  float res[8];
  #pragma unroll
  for (int q = 0; q < 8; ++q) res[q] = 0.f;
  for (int cc = 0; cc < 16; cc += 4) {
    int c = mq * 16 + cc;
    float4 f4 = *(const float4*)&selfF[pt * 64 + c];
    #pragma unroll
    for (int q = 0; q < 8; ++q) {
      const float4 w4 = *(const float4*)&Wout[(oo * 8 + q) * 64 + c];
      res[q] += w4.x * f4.x + w4.y * f4.y + w4.z * f4.z + w4.w * f4.w;
    }
  }
  #pragma unroll
  for (int q = 0; q < 8; ++q) {
    res[q] += __shfl_xor(res[q], 8);
    res[q] += __shfl_xor(res[q], 16);
  }
  if (mq == 0) {
    const int row = rowL[pt];
    float* out = hT + (size_t)row * 64 + oo * 8;
    #pragma unroll
    for (int q = 0; q < 8; ++q) {
      float vx = vmx[q];
      float g = 0.5f * vx * (1.f + erff(vx * 0.7071067811865476f));
      out[q] = g + res[q];
    }
  }
}

// ---------------- K4: BN statistics (deterministic two-stage) ----------------
__global__ __launch_bounds__(256) void k_bnstat(const float* __restrict__ hT,
                                                float* __restrict__ part) {
  const int bk = blockIdx.x;
  const int t = threadIdx.x;
  const int o = t & 63, rg = t >> 6;
  float s = 0.f, s2 = 0.f;
  for (int r = bk * 512 + rg; r < (bk + 1) * 512; r += 4) {
    float v = hT[(size_t)r * 64 + o];
    s += v;
    s2 = fmaf(v, v, s2);
  }
  __shared__ float ls[256], ls2[256];
  ls[t] = s; ls2[t] = s2;
  __syncthreads();
  if (t < 64) {
    float a  = ls[t] + ls[t + 64] + ls[t + 128] + ls[t + 192];
    float a2 = ls2[t] + ls2[t + 64] + ls2[t + 128] + ls2[t + 192];
    part[(bk * 64 + t) * 2]     = a;
    part[(bk * 64 + t) * 2 + 1] = a2;
  }
}

__global__ void k_bnfinal(const float* __restrict__ part, float* __restrict__ stats) {
  const int t = threadIdx.x;
  if (t < 64) {
    float s = 0.f, s2 = 0.f;
    for (int bk = 0; bk < 64; ++bk) {
      s  += part[(bk * 64 + t) * 2];
      s2 += part[(bk * 64 + t) * 2 + 1];
    }
    float mu  = s * (1.f / 32768.f);
    float var = s2 * (1.f / 32768.f) - mu * mu;
    stats[t * 2]     = mu;
    stats[t * 2 + 1] = 1.f / sqrtf(var + 1e-5f);
  }
}

// ---------------- K5: BN apply + transpose to (B,64,N) ----------------
__global__ __launch_bounds__(256) void k_bnapply(const float* __restrict__ hT,
                                                 const float* __restrict__ stats,
                                                 const float* __restrict__ gamma,
                                                 const float* __restrict__ beta,
                                                 float* __restrict__ out) {
  __shared__ float tile[64][65];
  __shared__ float sMu[64], sRs[64], sGa[64], sBe[64];
  const int t = threadIdx.x;
  const int r0 = blockIdx.x * 64;
  if (t < 64) {
    sMu[t] = stats[t * 2];
    sRs[t] = stats[t * 2 + 1];
    sGa[t] = gamma[t];
    sBe[t] = beta[t];
  }
  __syncthreads();
  for (int i = t; i < 4096; i += 256) {
    int rl = i >> 6, o = i & 63;
    float v = hT[(size_t)(r0 + rl) * 64 + o];
    tile[rl][o] = fmaf((v - sMu[o]) * sRs[o], sGa[o], sBe[o]);
  }
  __syncthreads();
  const int b = r0 >> 11, n0 = r0 & 2047;
  for (int i = t; i < 4096; i += 256) {
    int o = i >> 6, nl = i & 63;
    out[((size_t)b * 64 + o) * 2048 + n0 + nl] = tile[nl][o];
  }
}

// ---------------- launch ----------------
extern "C" void kernel_launch(void* const* d_in, const int* in_sizes, int n_in,
                              void* d_out, int out_size, void* d_ws, size_t ws_size,
                              hipStream_t stream) {
  const float* x       = (const float*)d_in[0];
  const float* feature = (const float*)d_in[1];
  const float* A       = (const float*)d_in[2];
  const float* Bf      = (const float*)d_in[3];
  const float* kern    = (const float*)d_in[4];
  const float* onePad  = (const float*)d_in[5];
  const float* Wmlp    = (const float*)d_in[6];
  const float* bmlp    = (const float*)d_in[7];
  const float* W1      = (const float*)d_in[8];
  const float* b1      = (const float*)d_in[9];
  const float* gamma   = (const float*)d_in[10];
  const float* beta    = (const float*)d_in[11];
  const float* Wout    = (const float*)d_in[12];

  char* ws = (char*)d_ws;
  float* rec     = (float*)(ws);                 // 32768*88*4   = 11,534,336
  int*   idxA    = (int*)  (ws + 11534336);      // 32768*20*4   =  2,621,440
  float* featN   = (float*)(ws + 14155776);      // 32768*64*4   =  8,388,608
  float* hT      = (float*)(ws + 22544384);      // 32768*64*4   =  8,388,608
  float* W1P     = (float*)(ws + 30932992);      // 192*64*4     =     49,152
  float* mmPart  = (float*)(ws + 30982144);      // 8192*2*4     =     65,536
  float* scal    = (float*)(ws + 31047680);      // 64*4         =        256
  float* bnPart  = (float*)(ws + 31047936);      // 64*64*2*4    =     32,768
  float* bnStats = (float*)(ws + 31080704);      // 64*2*4       =        512

  k_knn<<<dim3(512, 16), 256, 0, stream>>>(x, rec, idxA, mmPart);
  k_prep<<<1, 256, 0, stream>>>(A, kern, W1, mmPart, scal, W1P);
  k_transpose<<<dim3(32, 16), 256, 0, stream>>>(feature, featN);
  k_main<<<4096, 256, 0, stream>>>(rec, idxA, featN, scal, W1P, Bf, onePad,
                                   Wmlp, bmlp, b1, Wout, hT);
  k_bnstat<<<64, 256, 0, stream>>>(hT, bnPart);
  k_bnfinal<<<1, 64, 0, stream>>>(bnPart, bnStats);
  k_bnapply<<<512, 256, 0, stream>>>(hT, bnStats, gamma, beta, (float*)d_out);
}

// Round 2
// 397.720 us; speedup vs baseline: 2.2000x; 2.2000x over previous
//
#include <hip/hip_runtime.h>
#include <math.h>

typedef __attribute__((ext_vector_type(8))) short short8v;
typedef __attribute__((ext_vector_type(4))) float float4v;

static __device__ __forceinline__ unsigned short f2bf(float f) {
  union { float f; unsigned int u; } v; v.f = f;
  unsigned int r = v.u + 0x7fffu + ((v.u >> 16) & 1u);
  return (unsigned short)(r >> 16);
}
static __device__ __forceinline__ float bf2f(unsigned short h) {
  union { unsigned int u; float f; } v; v.u = ((unsigned int)h) << 16;
  return v.f;
}
static __device__ __forceinline__ void wave_fence() {
  asm volatile("s_waitcnt lgkmcnt(0)" ::: "memory");
}

// ---------------- K1: KNN + rel/dis records + minmax partials ----------------
__global__ __launch_bounds__(256) void k_knn(const float* __restrict__ x,
                                             float* __restrict__ rec,
                                             int*   __restrict__ idxArr,
                                             float* __restrict__ mmPart) {
  __shared__ float px[2048], py[2048], pz[2048];
  __shared__ float listD[4][64];
  __shared__ int   listJ[4][64];
  __shared__ int   cnt[4];
  __shared__ float selD[4][20];
  __shared__ int   selJ[4][20];
  __shared__ float wmn[4], wmx[4];

  const int b = blockIdx.y;
  const int t = threadIdx.x;
  const float* xb = x + (size_t)b * 3 * 2048;
  for (int i = t; i < 2048; i += 256) {
    px[i] = xb[i];
    py[i] = xb[2048 + i];
    pz[i] = xb[4096 + i];
  }
  __syncthreads();

  const int w = t >> 6, lane = t & 63;
  const int n = blockIdx.x * 4 + w;
  const float sx = px[n], sy = py[n], sz = pz[n];

  float lmin = 1e30f;
  for (int j = lane; j < 2048; j += 64) {
    float dx = px[j] - sx, dy = py[j] - sy, dz = pz[j] - sz;
    float d = fmaf(dx, dx, fmaf(dy, dy, dz * dz));
    lmin = fminf(lmin, d);
  }
  float v = lmin, T = 0.f;
  for (int r = 0; r < 20; ++r) {
    float m = v;
    for (int s = 1; s < 64; s <<= 1) m = fminf(m, __shfl_xor(m, s));
    unsigned long long mask = __ballot(v == m);
    int winner = (int)__builtin_ctzll(mask);
    if (lane == winner) v = 1e30f;
    T = m;
  }
  if (lane == 0) cnt[w] = 0;
  for (int j = lane; j < 2048; j += 64) {
    float dx = px[j] - sx, dy = py[j] - sy, dz = pz[j] - sz;
    float d = fmaf(dx, dx, fmaf(dy, dy, dz * dz));
    if (d <= T) {
      int slot = atomicAdd(&cnt[w], 1);
      if (slot < 64) { listD[w][slot] = d; listJ[w][slot] = j; }
    }
  }
  int M = cnt[w];

  if (M > 64) {
    float lastD = -1.f; int lastJ = -1;
    for (int r = 0; r < 20; ++r) {
      float bd = 1e30f; int bj = 0x7fffffff;
      for (int j = lane; j < 2048; j += 64) {
        float dx = px[j] - sx, dy = py[j] - sy, dz = pz[j] - sz;
        float d = fmaf(dx, dx, fmaf(dy, dy, dz * dz));
        bool valid = (d > lastD) || (d == lastD && j > lastJ);
        if (valid && (d < bd || (d == bd && j < bj))) { bd = d; bj = j; }
      }
      for (int s = 1; s < 64; s <<= 1) {
        float od = __shfl_xor(bd, s); int oj = __shfl_xor(bj, s);
        if (od < bd || (od == bd && oj < bj)) { bd = od; bj = oj; }
      }
      if (lane == 0) { selD[w][r] = bd; selJ[w][r] = bj; }
      lastD = bd; lastJ = bj;
    }
  } else {
    float d = (lane < M) ? listD[w][lane] : 1e30f;
    int   j = (lane < M) ? listJ[w][lane] : 0x7fffffff;
    float lastD = -1.f; int lastJ = -1;
    for (int r = 0; r < 20; ++r) {
      bool valid = (d > lastD) || (d == lastD && j > lastJ);
      float bd = valid ? d : 1e30f;
      int   bj = valid ? j : 0x7fffffff;
      for (int s = 1; s < 64; s <<= 1) {
        float od = __shfl_xor(bd, s); int oj = __shfl_xor(bj, s);
        if (od < bd || (od == bd && oj < bj)) { bd = od; bj = oj; }
      }
      if (lane == 0) { selD[w][r] = bd; selJ[w][r] = bj; }
      lastD = bd; lastJ = bj;
    }
  }
  __syncthreads();

  float row_mn = 1e30f, row_mx = -1e30f;
  const size_t row = (size_t)b * 2048 + n;
  if (lane < 20) {
    int   j = selJ[w][lane];
    float d = selD[w][lane];
    idxArr[row * 20 + lane] = j;
    float rx = px[j] - sx, ry = py[j] - sy, rz = pz[j] - sz;
    float dis = sqrtf(d);
    float* rp = rec + row * 88;
    rp[4 + lane]  = dis;
    rp[24 + lane] = rx;
    rp[44 + lane] = ry;
    rp[64 + lane] = rz;
    row_mn = fminf(fminf(rx, ry), fminf(rz, dis));
    row_mx = fmaxf(fmaxf(rx, ry), fmaxf(rz, dis));
    if (lane == 0) {
      rp[0] = sx; rp[1] = sy; rp[2] = sz; rp[3] = 0.f;
      row_mn = fminf(row_mn, fminf(fminf(sx, sy), sz));
      row_mx = fmaxf(row_mx, fmaxf(fmaxf(sx, sy), sz));
    }
  }
  for (int s = 1; s < 64; s <<= 1) {
    row_mn = fminf(row_mn, __shfl_xor(row_mn, s));
    row_mx = fmaxf(row_mx, __shfl_xor(row_mx, s));
  }
  if (lane == 0) { wmn[w] = row_mn; wmx[w] = row_mx; }
  __syncthreads();
  if (t == 0) {
    float mn = fminf(fminf(wmn[0], wmn[1]), fminf(wmn[2], wmn[3]));
    float mx = fmaxf(fmaxf(wmx[0], wmx[1]), fmaxf(wmx[2], wmx[3]));
    int bid = blockIdx.y * 512 + blockIdx.x;
    mmPart[bid * 2]     = mn;
    mmPart[bid * 2 + 1] = mx;
  }
}

// ---------------- K1b: minmax reduce, M matrix, bf16 weight prep ----------------
__global__ __launch_bounds__(256) void k_prep(const float* __restrict__ A,
                                              const float* __restrict__ kern,
                                              const float* __restrict__ W1,
                                              const float* __restrict__ Wmlp,
                                              const float* __restrict__ Wout,
                                              const float* __restrict__ mmPart,
                                              float* __restrict__ scal,
                                              unsigned short* __restrict__ W1Bg,
                                              unsigned short* __restrict__ WmBg,
                                              float* __restrict__ WoutT) {
  __shared__ float smn[256], smx[256];
  const int t = threadIdx.x;
  float mn = 1e30f, mx = -1e30f;
  for (int i = t; i < 8192; i += 256) {
    mn = fminf(mn, mmPart[i * 2]);
    mx = fmaxf(mx, mmPart[i * 2 + 1]);
  }
  smn[t] = mn; smx[t] = mx;
  __syncthreads();
  for (int s = 128; s > 0; s >>= 1) {
    if (t < s) { smn[t] = fminf(smn[t], smn[t + s]); smx[t] = fmaxf(smx[t], smx[t + s]); }
    __syncthreads();
  }
  if (t == 0) scal[0] = smn[0] / (smx[0] - smn[0]);   // c  (ref precedence: x - mn/(mx-mn))
  if (t < 24) {
    int d = t >> 3, e = t & 7;
    float s = 0.f;
    for (int d2 = 0; d2 < 3; ++d2)
      s += 0.5f * (A[d * 3 + d2] + A[d2 * 3 + d]) * kern[d2 * 8 + e];
    scal[1 + t] = s;
  }
  // W1B[o][u] = bf16(W1[o][c'(u)]),  c'(u) = (u%48)*4 + u/48  (feats shuffle folded in)
  for (int i = t; i < 12288; i += 256) {
    int o = i / 192, u = i % 192;
    int g = u / 48, r = u % 48;
    W1Bg[i] = f2bf(W1[o * 192 + r * 4 + g]);
  }
  for (int i = t; i < 2048; i += 256) WmBg[i] = f2bf(Wmlp[i]);
  for (int i = t; i < 4096; i += 256) {
    int c = i >> 6, o = i & 63;
    WoutT[c * 64 + o] = Wout[o * 64 + c];
  }
}

// ---------------- K2: transpose feature (B,64,N) -> featN (B,N,64) ----------------
__global__ __launch_bounds__(256) void k_transpose(const float* __restrict__ f,
                                                   float* __restrict__ fN) {
  __shared__ float tile[64][65];
  const int b = blockIdx.y, n0 = blockIdx.x * 64, t = threadIdx.x;
  const float* fb = f + (size_t)b * 64 * 2048;
  for (int i = t; i < 4096; i += 256) {
    int c = i >> 6, nl = i & 63;
    tile[c][nl] = fb[c * 2048 + n0 + nl];
  }
  __syncthreads();
  float* out = fN + ((size_t)b * 2048 + n0) * 64;
  for (int i = t; i < 4096; i += 256) {
    int nl = i >> 6, c = i & 63;
    out[nl * 64 + c] = tile[c][nl];
  }
}

// ---------------- K3: main, wave-per-point + MFMA ----------------
struct SMem {
  unsigned short WmB[32 * 80];          // 5120  (Wmlp bf16, stride 80 for aligned b128 frags)
  unsigned short aggB[32 * 200];        // 12800 (A-matrix for h-MFMA: 32 rows (pt,e) x K=192)
  union {
    unsigned short ffb[4][32 * 80];     // per-wave sin|cos bf16 (rows=k-slot, cols=64)
    float hB[32 * 68];                  // h pre-max (reused after ffb is dead)
  } u;                                  // 20480
  unsigned short xmLb[4][32 * 22];      // 5632  x_mlp bf16 [o][k]
  float recL[4][96];                    // 1536
  float permL[4][160];                  // 2560  perm [k][e]
  float f0L[4][64];                     // 1024
  float colsumL[4][8];                  // 128
  int   idxL[4][20];                    // 320
};                                      // total 49600 B -> 3 blocks/CU

__global__ __launch_bounds__(256, 3) void k_main(const float* __restrict__ rec,
    const int* __restrict__ idxArr, const float* __restrict__ featN,
    const float* __restrict__ scal, const unsigned short* __restrict__ W1Bg,
    const unsigned short* __restrict__ WmBg, const float* __restrict__ WoutT,
    const float* __restrict__ Bf, const float* __restrict__ onePad,
    const float* __restrict__ bmlp, const float* __restrict__ b1,
    float* __restrict__ hT) {
  __shared__ __align__(16) SMem sm;
  const int t = threadIdx.x;
  const int pt = t >> 6, lane = t & 63;
  const int row = blockIdx.x * 4 + pt;
  const int b = row >> 11;

  // block-constant: WmB (stride 64 -> 80)
  for (int i = t; i < 2048; i += 256)
    sm.WmB[(i >> 6) * 80 + (i & 63)] = WmBg[i];

  // per-wave loads
  if (lane < 20) sm.idxL[pt][lane] = idxArr[(size_t)row * 20 + lane];
  sm.recL[pt][lane] = rec[(size_t)row * 88 + lane];
  if (lane < 24) sm.recL[pt][64 + lane] = rec[(size_t)row * 88 + 64 + lane];

  // zero ffb rows 20..31 cols 0..63 (MFMA M-pad)
  {
    short8v z = {0, 0, 0, 0, 0, 0, 0, 0};
    *(short8v*)&sm.u.ffb[pt][(20 + (lane >> 3)) * 80 + (lane & 7) * 8] = z;
    if (lane < 32)
      *(short8v*)&sm.u.ffb[pt][(28 + (lane >> 3)) * 80 + (lane & 7) * 8] = z;
  }

  // per-lane register preloads
  const int m31 = lane & 31;
  float bf_[7];
  #pragma unroll
  for (int d = 0; d < 7; ++d) bf_[d] = Bf[d * 32 + m31];
  const float c0 = scal[0];
  const int e7 = lane & 7;
  const float M0 = scal[1 + e7], M1 = scal[9 + e7], M2 = scal[17 + e7];
  const float bm0 = bmlp[lane & 15], bm1 = bmlp[16 + (lane & 15)];

  __syncthreads();

  // ---- Fourier features -> ffb (bf16) ----
  {
    const float rpx = sm.recL[pt][0] - c0, rpy = sm.recL[pt][1] - c0, rpz = sm.recL[pt][2] - c0;
    const float basev = rpx * bf_[0] + rpy * bf_[1] + rpz * bf_[2];
    const int khalf = lane >> 5;
    #pragma unroll
    for (int it = 0; it < 10; ++it) {
      int k = khalf + 2 * it;
      float dis = sm.recL[pt][4 + k] - c0;
      float rx  = sm.recL[pt][24 + k] - c0;
      float ry  = sm.recL[pt][44 + k] - c0;
      float rz  = sm.recL[pt][64 + k] - c0;
      float s = basev + rx * bf_[3] + ry * bf_[4] + rz * bf_[5] + dis * bf_[6];
      float th = 6.283185307179586f * s;
      float sv, cv; __sincosf(th, &sv, &cv);
      sm.u.ffb[pt][k * 80 + m31]      = f2bf(sv);
      sm.u.ffb[pt][k * 80 + 32 + m31] = f2bf(cv);
    }
  }

  // ---- perm logits ----
  #pragma unroll
  for (int it = 0; it < 3; ++it) {
    int i = lane + 64 * it;
    if (i < 160) {
      int k = i >> 3;
      float v = sm.recL[pt][24 + k] * M0 + sm.recL[pt][44 + k] * M1
              + sm.recL[pt][64 + k] * M2 + onePad[k * 8 + e7];
      sm.permL[pt][k * 8 + e7] = v;
    }
  }
  wave_fence();

  // ---- topkmax softmax over k (8 lanes, 3 passes, no pv[] array) ----
  if (lane < 8) {
    float mx = -1e30f;
    #pragma unroll
    for (int k = 0; k < 20; ++k) mx = fmaxf(mx, sm.permL[pt][k * 8 + lane]);
    float s1 = 0.f;
    #pragma unroll
    for (int k = 0; k < 20; ++k) s1 += __expf(sm.permL[pt][k * 8 + lane] - mx);
    float inv = 1.f / s1, s2 = 0.f;
    #pragma unroll
    for (int k = 0; k < 20; ++k) {
      float q = __expf(sm.permL[pt][k * 8 + lane] - mx) * inv;
      if (q > 0.05f) s2 += q;
    }
    float inv2 = 1.f / (s2 + 1e-6f);
    #pragma unroll
    for (int k = 0; k < 20; ++k) {
      float q = __expf(sm.permL[pt][k * 8 + lane] - mx) * inv;
      q = (q > 0.05f) ? q : 0.f;
      sm.permL[pt][k * 8 + lane] = q * inv2;
    }
    sm.colsumL[pt][lane] = s2 * inv2;
  }
  wave_fence();

  // ---- x_mlp via MFMA: (k=20pad32 x K=64) @ WmlpT(K=64 x o=32) ----
  const int fr = lane & 15, fg = lane >> 4;
  {
    float4v acc[2][2];
    acc[0][0] = float4v{bm0, bm0, bm0, bm0};
    acc[0][1] = float4v{bm1, bm1, bm1, bm1};
    acc[1][0] = float4v{bm0, bm0, bm0, bm0};
    acc[1][1] = float4v{bm1, bm1, bm1, bm1};
    #pragma unroll
    for (int ks = 0; ks < 2; ++ks) {
      short8v a0 = *(const short8v*)&sm.u.ffb[pt][fr * 80 + ks * 32 + fg * 8];
      short8v a1 = *(const short8v*)&sm.u.ffb[pt][(16 + fr) * 80 + ks * 32 + fg * 8];
      short8v b0 = *(const short8v*)&sm.WmB[fr * 80 + ks * 32 + fg * 8];
      short8v b1v = *(const short8v*)&sm.WmB[(16 + fr) * 80 + ks * 32 + fg * 8];
      acc[0][0] = __builtin_amdgcn_mfma_f32_16x16x32_bf16(a0, b0,  acc[0][0], 0, 0, 0);
      acc[0][1] = __builtin_amdgcn_mfma_f32_16x16x32_bf16(a0, b1v, acc[0][1], 0, 0, 0);
      acc[1][0] = __builtin_amdgcn_mfma_f32_16x16x32_bf16(a1, b0,  acc[1][0], 0, 0, 0);
      acc[1][1] = __builtin_amdgcn_mfma_f32_16x16x32_bf16(a1, b1v, acc[1][1], 0, 0, 0);
    }
    #pragma unroll
    for (int mt = 0; mt < 2; ++mt)
      #pragma unroll
      for (int nt = 0; nt < 2; ++nt)
        #pragma unroll
        for (int rg = 0; rg < 4; ++rg) {
          int kk = mt * 16 + 4 * fg + rg;
          if (kk < 20)
            sm.xmLb[pt][(nt * 16 + fr) * 22 + kk] = f2bf(acc[mt][nt][rg]);
        }
  }
  wave_fence();

  // ---- gather + aggregation -> aggB (bf16 A-matrix) ----
  float cs[8];
  {
    float4v c01 = *(const float4v*)&sm.colsumL[pt][0];
    float4v c23 = *(const float4v*)&sm.colsumL[pt][4];
    cs[0] = c01[0]; cs[1] = c01[1]; cs[2] = c01[2]; cs[3] = c01[3];
    cs[4] = c23[0]; cs[5] = c23[1]; cs[6] = c23[2]; cs[7] = c23[3];
  }
  {
    float acc[8];
    #pragma unroll
    for (int e = 0; e < 8; ++e) acc[e] = 0.f;
    float f0 = 0.f;
    const float* fNb = featN + (((size_t)b << 11) * 64);
    #pragma unroll
    for (int k = 0; k < 20; ++k) {
      int j = sm.idxL[pt][k];
      float v = fNb[j * 64 + lane];
      if (k == 0) f0 = v;
      float4v p0 = *(const float4v*)&sm.permL[pt][k * 8];
      float4v p1 = *(const float4v*)&sm.permL[pt][k * 8 + 4];
      acc[0] = fmaf(v, p0[0], acc[0]); acc[1] = fmaf(v, p0[1], acc[1]);
      acc[2] = fmaf(v, p0[2], acc[2]); acc[3] = fmaf(v, p0[3], acc[3]);
      acc[4] = fmaf(v, p1[0], acc[4]); acc[5] = fmaf(v, p1[1], acc[5]);
      acc[6] = fmaf(v, p1[2], acc[6]); acc[7] = fmaf(v, p1[3], acc[7]);
    }
    sm.f0L[pt][lane] = f0;
    #pragma unroll
    for (int e = 0; e < 8; ++e) {
      float repv = f0 * cs[e];
      sm.aggB[(pt * 8 + e) * 200 + lane]      = f2bf(repv);          // u = lane (rep, f_neigh)
      sm.aggB[(pt * 8 + e) * 200 + 96 + lane] = f2bf(acc[e] - repv); // u = 96+lane (diff)
    }
  }
  {
    const int o2 = lane & 31, hf = lane >> 5;
    float accX[8];
    #pragma unroll
    for (int e = 0; e < 8; ++e) accX[e] = 0.f;
    #pragma unroll
    for (int kk = 0; kk < 10; ++kk) {
      int k = hf * 10 + kk;
      float xv = bf2f(sm.xmLb[pt][o2 * 22 + k]);
      float4v p0 = *(const float4v*)&sm.permL[pt][k * 8];
      float4v p1 = *(const float4v*)&sm.permL[pt][k * 8 + 4];
      accX[0] = fmaf(xv, p0[0], accX[0]); accX[1] = fmaf(xv, p0[1], accX[1]);
      accX[2] = fmaf(xv, p0[2], accX[2]); accX[3] = fmaf(xv, p0[3], accX[3]);
      accX[4] = fmaf(xv, p1[0], accX[4]); accX[5] = fmaf(xv, p1[1], accX[5]);
      accX[6] = fmaf(xv, p1[2], accX[6]); accX[7] = fmaf(xv, p1[3], accX[7]);
    }
    #pragma unroll
    for (int e = 0; e < 8; ++e) accX[e] += __shfl_xor(accX[e], 32);
    float xm0 = bf2f(sm.xmLb[pt][o2 * 22]);
    if (hf == 0) {
      #pragma unroll
      for (int e = 0; e < 8; ++e)
        sm.aggB[(pt * 8 + e) * 200 + 64 + o2] = f2bf(xm0 * cs[e]);          // u = 64+o (rep, x_mlp)
    } else {
      #pragma unroll
      for (int e = 0; e < 8; ++e)
        sm.aggB[(pt * 8 + e) * 200 + 160 + o2] = f2bf(accX[e] - xm0 * cs[e]); // u = 160+o (diff)
    }
  }
  __syncthreads();

  // ---- h-stage MFMA: (32 x 192) @ W1B^T(192 x 64) ----
  {
    const int mt = pt & 1, ntb = (pt >> 1) * 2;
    float4v h0 = float4v{0.f, 0.f, 0.f, 0.f};
    float4v h1 = float4v{0.f, 0.f, 0.f, 0.f};
    const unsigned short* w1p0 = W1Bg + ((ntb * 16 + fr) * 192);
    const unsigned short* w1p1 = W1Bg + (((ntb + 1) * 16 + fr) * 192);
    #pragma unroll
    for (int ks = 0; ks < 6; ++ks) {
      short8v a  = *(const short8v*)&sm.aggB[(mt * 16 + fr) * 200 + ks * 32 + fg * 8];
      short8v b0 = *(const short8v*)(w1p0 + ks * 32 + fg * 8);
      short8v b1v = *(const short8v*)(w1p1 + ks * 32 + fg * 8);
      h0 = __builtin_amdgcn_mfma_f32_16x16x32_bf16(a, b0,  h0, 0, 0, 0);
      h1 = __builtin_amdgcn_mfma_f32_16x16x32_bf16(a, b1v, h1, 0, 0, 0);
    }
    #pragma unroll
    for (int rg = 0; rg < 4; ++rg) {
      int m = mt * 16 + 4 * fg + rg;
      sm.u.hB[m * 68 + ntb * 16 + fr]       = h0[rg];
      sm.u.hB[m * 68 + (ntb + 1) * 16 + fr] = h1[rg];
    }
  }
  __syncthreads();

  // ---- post: max over e, +b1, gelu, residual, store ----
  {
    const int o = lane;
    float hm = sm.u.hB[(pt * 8) * 68 + o];
    #pragma unroll
    for (int e = 1; e < 8; ++e) hm = fmaxf(hm, sm.u.hB[(pt * 8 + e) * 68 + o]);
    hm += b1[o];
    float g = 0.5f * hm * (1.f + erff(hm * 0.7071067811865476f));
    float res = 0.f;
    #pragma unroll 8
    for (int c = 0; c < 64; ++c)
      res = fmaf(WoutT[c * 64 + o], sm.f0L[pt][c], res);
    hT[(size_t)row * 64 + o] = g + res;
  }
}

// ---------------- K4: BN statistics (deterministic two-stage) ----------------
__global__ __launch_bounds__(256) void k_bnstat(const float* __restrict__ hT,
                                                float* __restrict__ part) {
  const int bk = blockIdx.x;
  const int t = threadIdx.x;
  const int o = t & 63, rg = t >> 6;
  float s = 0.f, s2 = 0.f;
  for (int r = bk * 512 + rg; r < (bk + 1) * 512; r += 4) {
    float v = hT[(size_t)r * 64 + o];
    s += v;
    s2 = fmaf(v, v, s2);
  }
  __shared__ float ls[256], ls2[256];
  ls[t] = s; ls2[t] = s2;
  __syncthreads();
  if (t < 64) {
    float a  = ls[t] + ls[t + 64] + ls[t + 128] + ls[t + 192];
    float a2 = ls2[t] + ls2[t + 64] + ls2[t + 128] + ls2[t + 192];
    part[(bk * 64 + t) * 2]     = a;
    part[(bk * 64 + t) * 2 + 1] = a2;
  }
}

__global__ void k_bnfinal(const float* __restrict__ part, float* __restrict__ stats) {
  const int t = threadIdx.x;
  if (t < 64) {
    float s = 0.f, s2 = 0.f;
    for (int bk = 0; bk < 64; ++bk) {
      s  += part[(bk * 64 + t) * 2];
      s2 += part[(bk * 64 + t) * 2 + 1];
    }
    float mu  = s * (1.f / 32768.f);
    float var = s2 * (1.f / 32768.f) - mu * mu;
    stats[t * 2]     = mu;
    stats[t * 2 + 1] = 1.f / sqrtf(var + 1e-5f);
  }
}

// ---------------- K5: BN apply + transpose to (B,64,N) ----------------
__global__ __launch_bounds__(256) void k_bnapply(const float* __restrict__ hT,
                                                 const float* __restrict__ stats,
                                                 const float* __restrict__ gamma,
                                                 const float* __restrict__ beta,
                                                 float* __restrict__ out) {
  __shared__ float tile[64][65];
  __shared__ float sMu[64], sRs[64], sGa[64], sBe[64];
  const int t = threadIdx.x;
  const int r0 = blockIdx.x * 64;
  if (t < 64) {
    sMu[t] = stats[t * 2];
    sRs[t] = stats[t * 2 + 1];
    sGa[t] = gamma[t];
    sBe[t] = beta[t];
  }
  __syncthreads();
  for (int i = t; i < 4096; i += 256) {
    int rl = i >> 6, o = i & 63;
    float v = hT[(size_t)(r0 + rl) * 64 + o];
    tile[rl][o] = fmaf((v - sMu[o]) * sRs[o], sGa[o], sBe[o]);
  }
  __syncthreads();
  const int b = r0 >> 11, n0 = r0 & 2047;
  for (int i = t; i < 4096; i += 256) {
    int o = i >> 6, nl = i & 63;
    out[((size_t)b * 64 + o) * 2048 + n0 + nl] = tile[nl][o];
  }
}

// ---------------- launch ----------------
extern "C" void kernel_launch(void* const* d_in, const int* in_sizes, int n_in,
                              void* d_out, int out_size, void* d_ws, size_t ws_size,
                              hipStream_t stream) {
  const float* x       = (const float*)d_in[0];
  const float* feature = (const float*)d_in[1];
  const float* A       = (const float*)d_in[2];
  const float* Bf      = (const float*)d_in[3];
  const float* kern    = (const float*)d_in[4];
  const float* onePad  = (const float*)d_in[5];
  const float* Wmlp    = (const float*)d_in[6];
  const float* bmlp    = (const float*)d_in[7];
  const float* W1      = (const float*)d_in[8];
  const float* b1      = (const float*)d_in[9];
  const float* gamma   = (const float*)d_in[10];
  const float* beta    = (const float*)d_in[11];
  const float* Wout    = (const float*)d_in[12];

  char* ws = (char*)d_ws;
  float* rec             = (float*)(ws);                 // 32768*88*4 = 11,534,336
  int*   idxA            = (int*)  (ws + 11534336);      // 2,621,440  -> 14,155,776
  float* featN           = (float*)(ws + 14155776);      // 8,388,608  -> 22,544,384
  float* hT              = (float*)(ws + 22544384);      // 8,388,608  -> 30,932,992
  unsigned short* W1Bg   = (unsigned short*)(ws + 30932992); // 24,576 -> 30,957,568
  unsigned short* WmBg   = (unsigned short*)(ws + 30957568); // 4,096  -> 30,961,664
  float* WoutT           = (float*)(ws + 30961664);      // 16,384     -> 30,978,048
  float* mmPart          = (float*)(ws + 30978048);      // 65,536     -> 31,043,584
  float* scal            = (float*)(ws + 31043584);      // 256        -> 31,043,840
  float* bnPart          = (float*)(ws + 31043840);      // 32,768     -> 31,076,608
  float* bnStats         = (float*)(ws + 31076608);      // 512        -> 31,077,120

  k_knn<<<dim3(512, 16), 256, 0, stream>>>(x, rec, idxA, mmPart);
  k_prep<<<1, 256, 0, stream>>>(A, kern, W1, Wmlp, Wout, mmPart, scal, W1Bg, WmBg, WoutT);
  k_transpose<<<dim3(32, 16), 256, 0, stream>>>(feature, featN);
  k_main<<<8192, 256, 0, stream>>>(rec, idxA, featN, scal, W1Bg, WmBg, WoutT,
                                   Bf, onePad, bmlp, b1, hT);
  k_bnstat<<<64, 256, 0, stream>>>(hT, bnPart);
  k_bnfinal<<<1, 64, 0, stream>>>(bnPart, bnStats);
  k_bnapply<<<512, 256, 0, stream>>>(hT, bnStats, gamma, beta, (float*)d_out);
}

// Round 3
// 270.158 us; speedup vs baseline: 3.2388x; 1.4722x over previous
//
#include <hip/hip_runtime.h>
#include <math.h>

typedef __attribute__((ext_vector_type(8))) short short8v;
typedef __attribute__((ext_vector_type(4))) float float4v;

static __device__ __forceinline__ unsigned short f2bf(float f) {
  union { float f; unsigned int u; } v; v.f = f;
  unsigned int r = v.u + 0x7fffu + ((v.u >> 16) & 1u);
  return (unsigned short)(r >> 16);
}
static __device__ __forceinline__ float bf2f(unsigned short h) {
  union { unsigned int u; float f; } v; v.u = ((unsigned int)h) << 16;
  return v.f;
}
static __device__ __forceinline__ void wave_fence() {
  asm volatile("s_waitcnt lgkmcnt(0)" ::: "memory");
}

// ---------------- K1: KNN via bitonic selection ----------------
// grid (256,16), block 512: 8 waves/block, one row per wave. 100% wave occupancy.
__global__ __launch_bounds__(512) void k_knn(const float* __restrict__ x,
                                             float* __restrict__ rec,
                                             int*   __restrict__ idxArr,
                                             float* __restrict__ mmPart) {
  __shared__ float px[2048], py[2048], pz[2048];
  __shared__ unsigned long long listK[8][64];
  __shared__ float wmn[8], wmx[8];

  const int b = blockIdx.y;
  const int t = threadIdx.x;
  const float* xb = x + (size_t)b * 3 * 2048;
  for (int i = t; i < 2048; i += 512) {
    px[i] = xb[i];
    py[i] = xb[2048 + i];
    pz[i] = xb[4096 + i];
  }
  __syncthreads();

  const int w = t >> 6, lane = t & 63;
  const int n = blockIdx.x * 8 + w;
  const float sx = px[n], sy = py[n], sz = pz[n];

  // pass 1: per-lane min distance over its 32-candidate stripe
  float lmin = 1e30f;
  for (int j = lane; j < 2048; j += 64) {
    float dx = px[j] - sx, dy = py[j] - sy, dz = pz[j] - sz;
    float d = fmaf(dx, dx, fmaf(dy, dy, dz * dz));
    lmin = fminf(lmin, d);
  }
  // T = 20th smallest lane-min via 64-lane bitonic sort of u32 bits
  // (d >= 0 -> IEEE bits monotone). Guarantees >= 20 candidates <= T.
  unsigned k32 = __float_as_uint(lmin);
  #pragma unroll
  for (int kk = 2; kk <= 64; kk <<= 1) {
    #pragma unroll
    for (int jj = kk >> 1; jj > 0; jj >>= 1) {
      unsigned o = __shfl_xor(k32, jj);
      bool keepMin = (((lane & jj) == 0) == ((lane & kk) == 0));
      unsigned mn = k32 < o ? k32 : o;
      unsigned mx = k32 < o ? o : k32;
      k32 = keepMin ? mn : mx;
    }
  }
  const float T = __uint_as_float(__shfl(k32, 19));

  // pass 2: ballot-compact all candidates with d <= T into listK
  int base = 0;
  for (int j = lane; j < 2048; j += 64) {
    float dx = px[j] - sx, dy = py[j] - sy, dz = pz[j] - sz;
    float d = fmaf(dx, dx, fmaf(dy, dy, dz * dz));
    bool hit = (d <= T);
    unsigned long long mask = __ballot(hit);
    if (hit) {
      int slot = base + __popcll(mask & ((1ull << lane) - 1ull));
      if (slot < 64)
        listK[w][slot] = (((unsigned long long)__float_as_uint(d)) << 32) | (unsigned)j;
    }
    base += __popcll(mask);
  }
  const int M = base;

  float myD = 0.f; int myJ = 0;
  if (M > 64) {
    // exact fallback (expected never on random data): 20 full scans
    float lastD = -1.f; int lastJ = -1;
    for (int r = 0; r < 20; ++r) {
      float bd = 1e30f; int bj = 0x7fffffff;
      for (int j = lane; j < 2048; j += 64) {
        float dx = px[j] - sx, dy = py[j] - sy, dz = pz[j] - sz;
        float d = fmaf(dx, dx, fmaf(dy, dy, dz * dz));
        bool valid = (d > lastD) || (d == lastD && j > lastJ);
        if (valid && (d < bd || (d == bd && j < bj))) { bd = d; bj = j; }
      }
      for (int s = 1; s < 64; s <<= 1) {
        float od = __shfl_xor(bd, s); int oj = __shfl_xor(bj, s);
        if (od < bd || (od == bd && oj < bj)) { bd = od; bj = oj; }
      }
      if (lane == r) { myD = bd; myJ = bj; }
      lastD = bd; lastJ = bj;
    }
  } else {
    wave_fence();
    unsigned long long key = (lane < M) ? listK[w][lane] : 0xFFFFFFFFFFFFFFFFull;
    // 64-lane bitonic sort by (d_bits, j) lex -> lanes 0..19 hold top-20
    #pragma unroll
    for (int kk = 2; kk <= 64; kk <<= 1) {
      #pragma unroll
      for (int jj = kk >> 1; jj > 0; jj >>= 1) {
        unsigned long long o = __shfl_xor(key, jj);
        bool keepMin = (((lane & jj) == 0) == ((lane & kk) == 0));
        unsigned long long mn = key < o ? key : o;
        unsigned long long mx = key < o ? o : key;
        key = keepMin ? mn : mx;
      }
    }
    myD = __uint_as_float((unsigned)(key >> 32));
    myJ = (int)(unsigned)(key & 0xFFFFFFFFu);
  }

  // write records + per-row min/max contribution
  float row_mn = 1e30f, row_mx = -1e30f;
  const size_t row = (size_t)b * 2048 + n;
  if (lane < 20) {
    int j = myJ;
    idxArr[row * 20 + lane] = j;
    float rx = px[j] - sx, ry = py[j] - sy, rz = pz[j] - sz;
    float dis = sqrtf(myD);
    float* rp = rec + row * 88;
    rp[4 + lane]  = dis;
    rp[24 + lane] = rx;
    rp[44 + lane] = ry;
    rp[64 + lane] = rz;
    row_mn = fminf(fminf(rx, ry), fminf(rz, dis));
    row_mx = fmaxf(fmaxf(rx, ry), fmaxf(rz, dis));
    if (lane == 0) {
      rp[0] = sx; rp[1] = sy; rp[2] = sz; rp[3] = 0.f;
      row_mn = fminf(row_mn, fminf(fminf(sx, sy), sz));
      row_mx = fmaxf(row_mx, fmaxf(fmaxf(sx, sy), sz));
    }
  }
  for (int s = 1; s < 64; s <<= 1) {
    row_mn = fminf(row_mn, __shfl_xor(row_mn, s));
    row_mx = fmaxf(row_mx, __shfl_xor(row_mx, s));
  }
  if (lane == 0) { wmn[w] = row_mn; wmx[w] = row_mx; }
  __syncthreads();
  if (t == 0) {
    float mn = wmn[0], mx = wmx[0];
    #pragma unroll
    for (int i = 1; i < 8; ++i) { mn = fminf(mn, wmn[i]); mx = fmaxf(mx, wmx[i]); }
    int bid = blockIdx.y * 256 + blockIdx.x;
    mmPart[bid * 2]     = mn;
    mmPart[bid * 2 + 1] = mx;
  }
}

// ---------------- K1b: minmax reduce, M matrix, bf16 weight prep ----------------
__global__ __launch_bounds__(256) void k_prep(const float* __restrict__ A,
                                              const float* __restrict__ kern,
                                              const float* __restrict__ W1,
                                              const float* __restrict__ Wmlp,
                                              const float* __restrict__ Wout,
                                              const float* __restrict__ mmPart,
                                              float* __restrict__ scal,
                                              unsigned short* __restrict__ W1Bg,
                                              unsigned short* __restrict__ WmBg,
                                              float* __restrict__ WoutT) {
  __shared__ float smn[256], smx[256];
  const int t = threadIdx.x;
  float mn = 1e30f, mx = -1e30f;
  for (int i = t; i < 4096; i += 256) {
    mn = fminf(mn, mmPart[i * 2]);
    mx = fmaxf(mx, mmPart[i * 2 + 1]);
  }
  smn[t] = mn; smx[t] = mx;
  __syncthreads();
  for (int s = 128; s > 0; s >>= 1) {
    if (t < s) { smn[t] = fminf(smn[t], smn[t + s]); smx[t] = fmaxf(smx[t], smx[t + s]); }
    __syncthreads();
  }
  if (t == 0) scal[0] = smn[0] / (smx[0] - smn[0]);   // c  (ref precedence: x - mn/(mx-mn))
  if (t < 24) {
    int d = t >> 3, e = t & 7;
    float s = 0.f;
    for (int d2 = 0; d2 < 3; ++d2)
      s += 0.5f * (A[d * 3 + d2] + A[d2 * 3 + d]) * kern[d2 * 8 + e];
    scal[1 + t] = s;
  }
  // W1B[o][u] = bf16(W1[o][c'(u)]),  c'(u) = (u%48)*4 + u/48  (feats shuffle folded in)
  for (int i = t; i < 12288; i += 256) {
    int o = i / 192, u = i % 192;
    int g = u / 48, r = u % 48;
    W1Bg[i] = f2bf(W1[o * 192 + r * 4 + g]);
  }
  for (int i = t; i < 2048; i += 256) WmBg[i] = f2bf(Wmlp[i]);
  for (int i = t; i < 4096; i += 256) {
    int c = i >> 6, o = i & 63;
    WoutT[c * 64 + o] = Wout[o * 64 + c];
  }
}

// ---------------- K2: transpose feature (B,64,N) -> featN (B,N,64) ----------------
__global__ __launch_bounds__(256) void k_transpose(const float* __restrict__ f,
                                                   float* __restrict__ fN) {
  __shared__ float tile[64][65];
  const int b = blockIdx.y, n0 = blockIdx.x * 64, t = threadIdx.x;
  const float* fb = f + (size_t)b * 64 * 2048;
  for (int i = t; i < 4096; i += 256) {
    int c = i >> 6, nl = i & 63;
    tile[c][nl] = fb[c * 2048 + n0 + nl];
  }
  __syncthreads();
  float* out = fN + ((size_t)b * 2048 + n0) * 64;
  for (int i = t; i < 4096; i += 256) {
    int nl = i >> 6, c = i & 63;
    out[nl * 64 + c] = tile[c][nl];
  }
}

// ---------------- K3: main, wave-per-point + MFMA ----------------
struct SMem {
  unsigned short WmB[32 * 80];          // 5120  (Wmlp bf16, stride 80 for aligned b128 frags)
  unsigned short aggB[32 * 200];        // 12800 (A-matrix for h-MFMA: 32 rows (pt,e) x K=192)
  union {
    unsigned short ffb[4][32 * 80];     // per-wave sin|cos bf16 (rows=k-slot, cols=64)
    float hB[32 * 68];                  // h pre-max (reused after ffb is dead)
  } u;                                  // 20480
  unsigned short xmLb[4][32 * 22];      // 5632  x_mlp bf16 [o][k]
  float recL[4][96];                    // 1536
  float permL[4][160];                  // 2560  perm [k][e]
  float f0L[4][64];                     // 1024
  float colsumL[4][8];                  // 128
  int   idxL[4][20];                    // 320
};                                      // total 49600 B -> 3 blocks/CU

__global__ __launch_bounds__(256, 3) void k_main(const float* __restrict__ rec,
    const int* __restrict__ idxArr, const float* __restrict__ featN,
    const float* __restrict__ scal, const unsigned short* __restrict__ W1Bg,
    const unsigned short* __restrict__ WmBg, const float* __restrict__ WoutT,
    const float* __restrict__ Bf, const float* __restrict__ onePad,
    const float* __restrict__ bmlp, const float* __restrict__ b1,
    float* __restrict__ hT) {
  __shared__ __align__(16) SMem sm;
  const int t = threadIdx.x;
  const int pt = t >> 6, lane = t & 63;
  const int row = blockIdx.x * 4 + pt;
  const int b = row >> 11;

  // block-constant: WmB (stride 64 -> 80)
  for (int i = t; i < 2048; i += 256)
    sm.WmB[(i >> 6) * 80 + (i & 63)] = WmBg[i];

  // per-wave loads
  if (lane < 20) sm.idxL[pt][lane] = idxArr[(size_t)row * 20 + lane];
  sm.recL[pt][lane] = rec[(size_t)row * 88 + lane];
  if (lane < 24) sm.recL[pt][64 + lane] = rec[(size_t)row * 88 + 64 + lane];

  // zero ffb rows 20..31 cols 0..63 (MFMA M-pad)
  {
    short8v z = {0, 0, 0, 0, 0, 0, 0, 0};
    *(short8v*)&sm.u.ffb[pt][(20 + (lane >> 3)) * 80 + (lane & 7) * 8] = z;
    if (lane < 32)
      *(short8v*)&sm.u.ffb[pt][(28 + (lane >> 3)) * 80 + (lane & 7) * 8] = z;
  }

  // per-lane register preloads
  const int m31 = lane & 31;
  float bf_[7];
  #pragma unroll
  for (int d = 0; d < 7; ++d) bf_[d] = Bf[d * 32 + m31];
  const float c0 = scal[0];
  const int e7 = lane & 7;
  const float M0 = scal[1 + e7], M1 = scal[9 + e7], M2 = scal[17 + e7];
  const float bm0 = bmlp[lane & 15], bm1 = bmlp[16 + (lane & 15)];

  __syncthreads();

  // ---- Fourier features -> ffb (bf16) ----
  {
    const float rpx = sm.recL[pt][0] - c0, rpy = sm.recL[pt][1] - c0, rpz = sm.recL[pt][2] - c0;
    const float basev = rpx * bf_[0] + rpy * bf_[1] + rpz * bf_[2];
    const int khalf = lane >> 5;
    #pragma unroll
    for (int it = 0; it < 10; ++it) {
      int k = khalf + 2 * it;
      float dis = sm.recL[pt][4 + k] - c0;
      float rx  = sm.recL[pt][24 + k] - c0;
      float ry  = sm.recL[pt][44 + k] - c0;
      float rz  = sm.recL[pt][64 + k] - c0;
      float s = basev + rx * bf_[3] + ry * bf_[4] + rz * bf_[5] + dis * bf_[6];
      float th = 6.283185307179586f * s;
      float sv, cv; __sincosf(th, &sv, &cv);
      sm.u.ffb[pt][k * 80 + m31]      = f2bf(sv);
      sm.u.ffb[pt][k * 80 + 32 + m31] = f2bf(cv);
    }
  }

  // ---- perm logits ----
  #pragma unroll
  for (int it = 0; it < 3; ++it) {
    int i = lane + 64 * it;
    if (i < 160) {
      int k = i >> 3;
      float v = sm.recL[pt][24 + k] * M0 + sm.recL[pt][44 + k] * M1
              + sm.recL[pt][64 + k] * M2 + onePad[k * 8 + e7];
      sm.permL[pt][k * 8 + e7] = v;
    }
  }
  wave_fence();

  // ---- topkmax softmax over k (8 lanes, 3 passes, no pv[] array) ----
  if (lane < 8) {
    float mx = -1e30f;
    #pragma unroll
    for (int k = 0; k < 20; ++k) mx = fmaxf(mx, sm.permL[pt][k * 8 + lane]);
    float s1 = 0.f;
    #pragma unroll
    for (int k = 0; k < 20; ++k) s1 += __expf(sm.permL[pt][k * 8 + lane] - mx);
    float inv = 1.f / s1, s2 = 0.f;
    #pragma unroll
    for (int k = 0; k < 20; ++k) {
      float q = __expf(sm.permL[pt][k * 8 + lane] - mx) * inv;
      if (q > 0.05f) s2 += q;
    }
    float inv2 = 1.f / (s2 + 1e-6f);
    #pragma unroll
    for (int k = 0; k < 20; ++k) {
      float q = __expf(sm.permL[pt][k * 8 + lane] - mx) * inv;
      q = (q > 0.05f) ? q : 0.f;
      sm.permL[pt][k * 8 + lane] = q * inv2;
    }
    sm.colsumL[pt][lane] = s2 * inv2;
  }
  wave_fence();

  // ---- x_mlp via MFMA: (k=20pad32 x K=64) @ WmlpT(K=64 x o=32) ----
  const int fr = lane & 15, fg = lane >> 4;
  {
    float4v acc[2][2];
    acc[0][0] = float4v{bm0, bm0, bm0, bm0};
    acc[0][1] = float4v{bm1, bm1, bm1, bm1};
    acc[1][0] = float4v{bm0, bm0, bm0, bm0};
    acc[1][1] = float4v{bm1, bm1, bm1, bm1};
    #pragma unroll
    for (int ks = 0; ks < 2; ++ks) {
      short8v a0 = *(const short8v*)&sm.u.ffb[pt][fr * 80 + ks * 32 + fg * 8];
      short8v a1 = *(const short8v*)&sm.u.ffb[pt][(16 + fr) * 80 + ks * 32 + fg * 8];
      short8v b0 = *(const short8v*)&sm.WmB[fr * 80 + ks * 32 + fg * 8];
      short8v b1v = *(const short8v*)&sm.WmB[(16 + fr) * 80 + ks * 32 + fg * 8];
      acc[0][0] = __builtin_amdgcn_mfma_f32_16x16x32_bf16(a0, b0,  acc[0][0], 0, 0, 0);
      acc[0][1] = __builtin_amdgcn_mfma_f32_16x16x32_bf16(a0, b1v, acc[0][1], 0, 0, 0);
      acc[1][0] = __builtin_amdgcn_mfma_f32_16x16x32_bf16(a1, b0,  acc[1][0], 0, 0, 0);
      acc[1][1] = __builtin_amdgcn_mfma_f32_16x16x32_bf16(a1, b1v, acc[1][1], 0, 0, 0);
    }
    #pragma unroll
    for (int mt = 0; mt < 2; ++mt)
      #pragma unroll
      for (int nt = 0; nt < 2; ++nt)
        #pragma unroll
        for (int rg = 0; rg < 4; ++rg) {
          int kk = mt * 16 + 4 * fg + rg;
          if (kk < 20)
            sm.xmLb[pt][(nt * 16 + fr) * 22 + kk] = f2bf(acc[mt][nt][rg]);
        }
  }
  wave_fence();

  // ---- gather + aggregation -> aggB (bf16 A-matrix) ----
  float cs[8];
  {
    float4v c01 = *(const float4v*)&sm.colsumL[pt][0];
    float4v c23 = *(const float4v*)&sm.colsumL[pt][4];
    cs[0] = c01[0]; cs[1] = c01[1]; cs[2] = c01[2]; cs[3] = c01[3];
    cs[4] = c23[0]; cs[5] = c23[1]; cs[6] = c23[2]; cs[7] = c23[3];
  }
  {
    float acc[8];
    #pragma unroll
    for (int e = 0; e < 8; ++e) acc[e] = 0.f;
    float f0 = 0.f;
    const float* fNb = featN + (((size_t)b << 11) * 64);
    #pragma unroll
    for (int k = 0; k < 20; ++k) {
      int j = sm.idxL[pt][k];
      float v = fNb[j * 64 + lane];
      if (k == 0) f0 = v;
      float4v p0 = *(const float4v*)&sm.permL[pt][k * 8];
      float4v p1 = *(const float4v*)&sm.permL[pt][k * 8 + 4];
      acc[0] = fmaf(v, p0[0], acc[0]); acc[1] = fmaf(v, p0[1], acc[1]);
      acc[2] = fmaf(v, p0[2], acc[2]); acc[3] = fmaf(v, p0[3], acc[3]);
      acc[4] = fmaf(v, p1[0], acc[4]); acc[5] = fmaf(v, p1[1], acc[5]);
      acc[6] = fmaf(v, p1[2], acc[6]); acc[7] = fmaf(v, p1[3], acc[7]);
    }
    sm.f0L[pt][lane] = f0;
    #pragma unroll
    for (int e = 0; e < 8; ++e) {
      float repv = f0 * cs[e];
      sm.aggB[(pt * 8 + e) * 200 + lane]      = f2bf(repv);          // u = lane (rep, f_neigh)
      sm.aggB[(pt * 8 + e) * 200 + 96 + lane] = f2bf(acc[e] - repv); // u = 96+lane (diff)
    }
  }
  {
    const int o2 = lane & 31, hf = lane >> 5;
    float accX[8];
    #pragma unroll
    for (int e = 0; e < 8; ++e) accX[e] = 0.f;
    #pragma unroll
    for (int kk = 0; kk < 10; ++kk) {
      int k = hf * 10 + kk;
      float xv = bf2f(sm.xmLb[pt][o2 * 22 + k]);
      float4v p0 = *(const float4v*)&sm.permL[pt][k * 8];
      float4v p1 = *(const float4v*)&sm.permL[pt][k * 8 + 4];
      accX[0] = fmaf(xv, p0[0], accX[0]); accX[1] = fmaf(xv, p0[1], accX[1]);
      accX[2] = fmaf(xv, p0[2], accX[2]); accX[3] = fmaf(xv, p0[3], accX[3]);
      accX[4] = fmaf(xv, p1[0], accX[4]); accX[5] = fmaf(xv, p1[1], accX[5]);
      accX[6] = fmaf(xv, p1[2], accX[6]); accX[7] = fmaf(xv, p1[3], accX[7]);
    }
    #pragma unroll
    for (int e = 0; e < 8; ++e) accX[e] += __shfl_xor(accX[e], 32);
    float xm0 = bf2f(sm.xmLb[pt][o2 * 22]);
    if (hf == 0) {
      #pragma unroll
      for (int e = 0; e < 8; ++e)
        sm.aggB[(pt * 8 + e) * 200 + 64 + o2] = f2bf(xm0 * cs[e]);          // u = 64+o (rep, x_mlp)
    } else {
      #pragma unroll
      for (int e = 0; e < 8; ++e)
        sm.aggB[(pt * 8 + e) * 200 + 160 + o2] = f2bf(accX[e] - xm0 * cs[e]); // u = 160+o (diff)
    }
  }
  __syncthreads();

  // ---- h-stage MFMA: (32 x 192) @ W1B^T(192 x 64) ----
  {
    const int mt = pt & 1, ntb = (pt >> 1) * 2;
    float4v h0 = float4v{0.f, 0.f, 0.f, 0.f};
    float4v h1 = float4v{0.f, 0.f, 0.f, 0.f};
    const unsigned short* w1p0 = W1Bg + ((ntb * 16 + fr) * 192);
    const unsigned short* w1p1 = W1Bg + (((ntb + 1) * 16 + fr) * 192);
    #pragma unroll
    for (int ks = 0; ks < 6; ++ks) {
      short8v a  = *(const short8v*)&sm.aggB[(mt * 16 + fr) * 200 + ks * 32 + fg * 8];
      short8v b0 = *(const short8v*)(w1p0 + ks * 32 + fg * 8);
      short8v b1v = *(const short8v*)(w1p1 + ks * 32 + fg * 8);
      h0 = __builtin_amdgcn_mfma_f32_16x16x32_bf16(a, b0,  h0, 0, 0, 0);
      h1 = __builtin_amdgcn_mfma_f32_16x16x32_bf16(a, b1v, h1, 0, 0, 0);
    }
    #pragma unroll
    for (int rg = 0; rg < 4; ++rg) {
      int m = mt * 16 + 4 * fg + rg;
      sm.u.hB[m * 68 + ntb * 16 + fr]       = h0[rg];
      sm.u.hB[m * 68 + (ntb + 1) * 16 + fr] = h1[rg];
    }
  }
  __syncthreads();

  // ---- post: max over e, +b1, gelu, residual, store ----
  {
    const int o = lane;
    float hm = sm.u.hB[(pt * 8) * 68 + o];
    #pragma unroll
    for (int e = 1; e < 8; ++e) hm = fmaxf(hm, sm.u.hB[(pt * 8 + e) * 68 + o]);
    hm += b1[o];
    float g = 0.5f * hm * (1.f + erff(hm * 0.7071067811865476f));
    float res = 0.f;
    #pragma unroll 8
    for (int c = 0; c < 64; ++c)
      res = fmaf(WoutT[c * 64 + o], sm.f0L[pt][c], res);
    hT[(size_t)row * 64 + o] = g + res;
  }
}

// ---------------- K4: BN statistics (deterministic two-stage) ----------------
__global__ __launch_bounds__(256) void k_bnstat(const float* __restrict__ hT,
                                                float* __restrict__ part) {
  const int bk = blockIdx.x;
  const int t = threadIdx.x;
  const int o = t & 63, rg = t >> 6;
  float s = 0.f, s2 = 0.f;
  for (int r = bk * 512 + rg; r < (bk + 1) * 512; r += 4) {
    float v = hT[(size_t)r * 64 + o];
    s += v;
    s2 = fmaf(v, v, s2);
  }
  __shared__ float ls[256], ls2[256];
  ls[t] = s; ls2[t] = s2;
  __syncthreads();
  if (t < 64) {
    float a  = ls[t] + ls[t + 64] + ls[t + 128] + ls[t + 192];
    float a2 = ls2[t] + ls2[t + 64] + ls2[t + 128] + ls2[t + 192];
    part[(bk * 64 + t) * 2]     = a;
    part[(bk * 64 + t) * 2 + 1] = a2;
  }
}

__global__ void k_bnfinal(const float* __restrict__ part, float* __restrict__ stats) {
  const int t = threadIdx.x;
  if (t < 64) {
    float s = 0.f, s2 = 0.f;
    for (int bk = 0; bk < 64; ++bk) {
      s  += part[(bk * 64 + t) * 2];
      s2 += part[(bk * 64 + t) * 2 + 1];
    }
    float mu  = s * (1.f / 32768.f);
    float var = s2 * (1.f / 32768.f) - mu * mu;
    stats[t * 2]     = mu;
    stats[t * 2 + 1] = 1.f / sqrtf(var + 1e-5f);
  }
}

// ---------------- K5: BN apply + transpose to (B,64,N) ----------------
__global__ __launch_bounds__(256) void k_bnapply(const float* __restrict__ hT,
                                                 const float* __restrict__ stats,
                                                 const float* __restrict__ gamma,
                                                 const float* __restrict__ beta,
                                                 float* __restrict__ out) {
  __shared__ float tile[64][65];
  __shared__ float sMu[64], sRs[64], sGa[64], sBe[64];
  const int t = threadIdx.x;
  const int r0 = blockIdx.x * 64;
  if (t < 64) {
    sMu[t] = stats[t * 2];
    sRs[t] = stats[t * 2 + 1];
    sGa[t] = gamma[t];
    sBe[t] = beta[t];
  }
  __syncthreads();
  for (int i = t; i < 4096; i += 256) {
    int rl = i >> 6, o = i & 63;
    float v = hT[(size_t)(r0 + rl) * 64 + o];
    tile[rl][o] = fmaf((v - sMu[o]) * sRs[o], sGa[o], sBe[o]);
  }
  __syncthreads();
  const int b = r0 >> 11, n0 = r0 & 2047;
  for (int i = t; i < 4096; i += 256) {
    int o = i >> 6, nl = i & 63;
    out[((size_t)b * 64 + o) * 2048 + n0 + nl] = tile[nl][o];
  }
}

// ---------------- launch ----------------
extern "C" void kernel_launch(void* const* d_in, const int* in_sizes, int n_in,
                              void* d_out, int out_size, void* d_ws, size_t ws_size,
                              hipStream_t stream) {
  const float* x       = (const float*)d_in[0];
  const float* feature = (const float*)d_in[1];
  const float* A       = (const float*)d_in[2];
  const float* Bf      = (const float*)d_in[3];
  const float* kern    = (const float*)d_in[4];
  const float* onePad  = (const float*)d_in[5];
  const float* Wmlp    = (const float*)d_in[6];
  const float* bmlp    = (const float*)d_in[7];
  const float* W1      = (const float*)d_in[8];
  const float* b1      = (const float*)d_in[9];
  const float* gamma   = (const float*)d_in[10];
  const float* beta    = (const float*)d_in[11];
  const float* Wout    = (const float*)d_in[12];

  char* ws = (char*)d_ws;
  float* rec             = (float*)(ws);                 // 32768*88*4 = 11,534,336
  int*   idxA            = (int*)  (ws + 11534336);      // 2,621,440  -> 14,155,776
  float* featN           = (float*)(ws + 14155776);      // 8,388,608  -> 22,544,384
  float* hT              = (float*)(ws + 22544384);      // 8,388,608  -> 30,932,992
  unsigned short* W1Bg   = (unsigned short*)(ws + 30932992); // 24,576 -> 30,957,568
  unsigned short* WmBg   = (unsigned short*)(ws + 30957568); // 4,096  -> 30,961,664
  float* WoutT           = (float*)(ws + 30961664);      // 16,384     -> 30,978,048
  float* mmPart          = (float*)(ws + 30978048);      // 32,768     -> 31,010,816
  float* scal            = (float*)(ws + 31010816);      // 256        -> 31,011,072
  float* bnPart          = (float*)(ws + 31011072);      // 32,768     -> 31,043,840
  float* bnStats         = (float*)(ws + 31043840);      // 512        -> 31,044,352

  k_knn<<<dim3(256, 16), 512, 0, stream>>>(x, rec, idxA, mmPart);
  k_prep<<<1, 256, 0, stream>>>(A, kern, W1, Wmlp, Wout, mmPart, scal, W1Bg, WmBg, WoutT);
  k_transpose<<<dim3(32, 16), 256, 0, stream>>>(feature, featN);
  k_main<<<8192, 256, 0, stream>>>(rec, idxA, featN, scal, W1Bg, WmBg, WoutT,
                                   Bf, onePad, bmlp, b1, hT);
  k_bnstat<<<64, 256, 0, stream>>>(hT, bnPart);
  k_bnfinal<<<1, 64, 0, stream>>>(bnPart, bnStats);
  k_bnapply<<<512, 256, 0, stream>>>(hT, bnStats, gamma, beta, (float*)d_out);
}